// Round 2
// baseline (569.714 us; speedup 1.0000x reference)
//
#include <hip/hip_runtime.h>

#define BATCH 16
#define SEQ   2048
#define EMB   1024
#define DH    128
#define NTOK  (BATCH*SEQ)   // 32768

typedef _Float16 half4_t __attribute__((ext_vector_type(4)));
typedef _Float16 half8_t __attribute__((ext_vector_type(8)));
typedef float    f32x4   __attribute__((ext_vector_type(4)));

// ---------------- workspace layout (bytes) ----------------
// Wt   : 384*1024 f16 transposed weights (hi)   @ 0         (768 KB)
// Wlo  : 256*1024 f16 residual (q,k rows only)  @ 0xC0000   (512 KB)
// q_hi : [32768][128] f16 (scaled by 32*log2e)  @ 0x140000  (8 MB)
// q_lo : ...
#define OFF_WT  0u
#define OFF_WLO 0xC0000u
#define OFF_QHI 0x140000u
#define OFF_QLO (OFF_QHI + 0x800000u)
#define OFF_KHI (OFF_QLO + 0x800000u)
#define OFF_KLO (OFF_KHI + 0x800000u)
#define OFF_VT  (OFF_KLO + 0x800000u)

// ---------------- kernel 1: W -> Wt hi/lo (transposed, fp16) ----------------
// Wt rows 0..127 = Wq^T, 128..255 = Wk^T, 256..383 = Wv^T.
// Wlo holds the fp16 residual for the q,k rows (0..255) only.
__global__ void prep_w(const float* __restrict__ Wq, const float* __restrict__ Wk,
                       const float* __restrict__ Wv, _Float16* __restrict__ Wt,
                       _Float16* __restrict__ Wlo) {
    int r = blockIdx.x;            // 0..383
    int which = r >> 7;
    int d = r & 127;
    const float* W = (which == 0) ? Wq : ((which == 1) ? Wk : Wv);
    for (int e = threadIdx.x; e < EMB; e += blockDim.x) {
        float f = W[(size_t)e * DH + d];
        _Float16 h = (_Float16)f;
        Wt[(size_t)r * EMB + e] = h;
        if (which < 2)
            Wlo[(size_t)r * EMB + e] = (_Float16)(f - (float)h);
    }
}

// ---------------- kernel 2: QKV projection ----------------
// Per wave: 16 token rows x all 384 output cols. q,k cols use a 3-MFMA
// hi/lo scheme (xhi*Whi + xlo*Whi + xhi*Wlo -> ~2^-22 relative error);
// v cols single pass. q pre-scaled by 32*log2(e); q,k stored as fp16
// hi/lo pairs; v stored transposed [B][DH][SEQ].
__global__ __launch_bounds__(256) void proj_qkv(
    const float* __restrict__ x, const _Float16* __restrict__ Wt,
    const _Float16* __restrict__ Wlo,
    const float* __restrict__ bq, const float* __restrict__ bk,
    const float* __restrict__ bv,
    _Float16* __restrict__ qhi, _Float16* __restrict__ qlo,
    _Float16* __restrict__ khi, _Float16* __restrict__ klo,
    _Float16* __restrict__ vt) {
    const int lane = threadIdx.x & 63;
    const int w    = threadIdx.x >> 6;
    const int l15  = lane & 15, g = lane >> 4;
    const int m0   = (blockIdx.x * 4 + w) * 16;

    f32x4 acc[24];
#pragma unroll
    for (int i = 0; i < 24; ++i) acc[i] = {};

    const float*    xrow  = x   + (size_t)(m0 + l15) * EMB;
    const _Float16* wrow  = Wt  + (size_t)l15 * EMB;
    const _Float16* wlrow = Wlo + (size_t)l15 * EMB;

    for (int kc = 0; kc < EMB / 32; ++kc) {
        const int koff = kc * 32 + g * 8;
        f32x4 xa = *(const f32x4*)(xrow + koff);
        f32x4 xb = *(const f32x4*)(xrow + koff + 4);
        half8_t xhi, xlo;
#pragma unroll
        for (int j = 0; j < 4; ++j) {
            float f = xa[j]; _Float16 h = (_Float16)f;
            xhi[j] = h; xlo[j] = (_Float16)(f - (float)h);
            float f2 = xb[j]; _Float16 h2 = (_Float16)f2;
            xhi[j + 4] = h2; xlo[j + 4] = (_Float16)(f2 - (float)h2);
        }
#pragma unroll
        for (int nt = 0; nt < 24; ++nt) {
            half8_t bf = *(const half8_t*)(wrow + (size_t)nt * 16 * EMB + koff);
            acc[nt] = __builtin_amdgcn_mfma_f32_16x16x32_f16(xhi, bf, acc[nt], 0, 0, 0);
            if (nt < 16) {  // q,k: lo-passes for precision; v doesn't need them
                half8_t bl = *(const half8_t*)(wlrow + (size_t)nt * 16 * EMB + koff);
                acc[nt] = __builtin_amdgcn_mfma_f32_16x16x32_f16(xlo, bf, acc[nt], 0, 0, 0);
                acc[nt] = __builtin_amdgcn_mfma_f32_16x16x32_f16(xhi, bl, acc[nt], 0, 0, 0);
            }
        }
    }

    const float SC = 46.166241308446828f;  // 32 * log2(e), folded into q
#pragma unroll
    for (int nt = 0; nt < 24; ++nt) {
        const int n = nt * 16 + l15;
        if (nt < 8) {                       // ---- q ----
            const float bias = bq[n];
#pragma unroll
            for (int r = 0; r < 4; ++r) {
                const int m = m0 + g * 4 + r;
                float qv = (acc[nt][r] + bias) * SC;
                _Float16 h = (_Float16)qv;
                qhi[(size_t)m * DH + n] = h;
                qlo[(size_t)m * DH + n] = (_Float16)(qv - (float)h);
            }
        } else if (nt < 16) {               // ---- k ----
            const int d = n - 128;
            const float bias = bk[d];
#pragma unroll
            for (int r = 0; r < 4; ++r) {
                const int m = m0 + g * 4 + r;
                float kv = acc[nt][r] + bias;
                _Float16 h = (_Float16)kv;
                khi[(size_t)m * DH + d] = h;
                klo[(size_t)m * DH + d] = (_Float16)(kv - (float)h);
            }
        } else {                            // ---- v (transposed store) ----
            const int d  = n - 256;
            const float bias = bv[d];
            const int bb = m0 >> 11;
            const int s0 = (m0 & (SEQ - 1)) + g * 4;
            half4_t vv;
#pragma unroll
            for (int r = 0; r < 4; ++r) vv[r] = (_Float16)(acc[nt][r] + bias);
            *(half4_t*)(vt + (size_t)bb * DH * SEQ + (size_t)d * SEQ + s0) = vv;
        }
    }
}

// ---------------- kernel 3: causal flash attention ----------------
// 1 wave = 16 q rows. Swapped QK^T: S^T = mfma(K, Q) so lane holds
// S^T[k=(l>>4)*4+r][q=l&15]; softmax state per q at lane l&15; S^T C-tile is
// exactly the B-operand of 16x16x16_f16 PV (O^T = V^T * P^T) -> no shuffles.
__global__ __launch_bounds__(256) void attn(
    const _Float16* __restrict__ qhi, const _Float16* __restrict__ qlo,
    const _Float16* __restrict__ khi, const _Float16* __restrict__ klo,
    const _Float16* __restrict__ vt, float* __restrict__ out) {
    const int lane = threadIdx.x & 63;
    const int w    = threadIdx.x >> 6;
    const int l15  = lane & 15, g = lane >> 4;

    // XCD-aware decode: each XCD (gid&7) owns 2 batches -> K/V fits its L2.
    const int gid = blockIdx.x;
    const int xcd = gid & 7, ix = gid >> 3;
    const int b   = (xcd << 1) | (ix & 1);
    const int bx  = ix >> 1;                 // 0..31
    const int qt  = bx + w * 32;             // interleaved: balances causal work
    const int q0  = qt * 16;

    const size_t qrow = ((size_t)b * SEQ + q0 + l15) * DH;
    half8_t Qh[4], Ql[4];
#pragma unroll
    for (int kk = 0; kk < 4; ++kk) {
        Qh[kk] = *(const half8_t*)(qhi + qrow + kk * 32 + g * 8);
        Ql[kk] = *(const half8_t*)(qlo + qrow + kk * 32 + g * 8);
    }

    f32x4 o[8];
#pragma unroll
    for (int dt = 0; dt < 8; ++dt) o[dt] = {};
    float mrun = -3.0e38f, ell = 0.0f;

    const _Float16* kb_h  = khi + (size_t)b * SEQ * DH;
    const _Float16* kb_l  = klo + (size_t)b * SEQ * DH;
    const _Float16* vbase = vt  + (size_t)b * DH * SEQ;

    for (int t = 0; t <= qt; ++t) {
        const int kb = t * 16;
        const _Float16* krh = kb_h + (size_t)(kb + l15) * DH + g * 8;
        const _Float16* krl = kb_l + (size_t)(kb + l15) * DH + g * 8;

        f32x4 sa = {}, sb = {};
#pragma unroll
        for (int kk = 0; kk < 4; ++kk) {
            half8_t kh = *(const half8_t*)(krh + kk * 32);
            half8_t kl = *(const half8_t*)(krl + kk * 32);
            sa = __builtin_amdgcn_mfma_f32_16x16x32_f16(kh, Qh[kk], sa, 0, 0, 0);
            sb = __builtin_amdgcn_mfma_f32_16x16x32_f16(kl, Qh[kk], sb, 0, 0, 0);
            sb = __builtin_amdgcn_mfma_f32_16x16x32_f16(kh, Ql[kk], sb, 0, 0, 0);
        }
        f32x4 s = sa + sb;   // logits, already in log2-domain (scale folded)

        if (t == qt) {       // diagonal tile: causal mask
#pragma unroll
            for (int r = 0; r < 4; ++r)
                if (kb + g * 4 + r > q0 + l15) s[r] = -3.0e38f;
        }

        float mt = fmaxf(fmaxf(s[0], s[1]), fmaxf(s[2], s[3]));
        mt = fmaxf(mt, __shfl_xor(mt, 16, 64));
        mt = fmaxf(mt, __shfl_xor(mt, 32, 64));
        const float mnew  = fmaxf(mrun, mt);
        const float alpha = exp2f(mrun - mnew);
        const float p0 = exp2f(s[0] - mnew), p1 = exp2f(s[1] - mnew);
        const float p2 = exp2f(s[2] - mnew), p3 = exp2f(s[3] - mnew);
        float ps = p0 + p1 + p2 + p3;
        ps += __shfl_xor(ps, 16, 64);
        ps += __shfl_xor(ps, 32, 64);
        ell = ell * alpha + ps;
        mrun = mnew;

        half4_t pf;
        pf[0] = (_Float16)p0; pf[1] = (_Float16)p1;
        pf[2] = (_Float16)p2; pf[3] = (_Float16)p3;

        const _Float16* vcol = vbase + (size_t)l15 * SEQ + kb + g * 4;
#pragma unroll
        for (int dt = 0; dt < 8; ++dt) {
            half4_t vf = *(const half4_t*)(vcol + (size_t)dt * 16 * SEQ);
            o[dt][0] *= alpha; o[dt][1] *= alpha;
            o[dt][2] *= alpha; o[dt][3] *= alpha;
            o[dt] = __builtin_amdgcn_mfma_f32_16x16x16f16(vf, pf, o[dt], 0, 0, 0);
        }
    }

    const float rinv = 1.0f / ell;
    float* orow = out + ((size_t)b * SEQ + q0 + l15) * DH + g * 4;
#pragma unroll
    for (int dt = 0; dt < 8; ++dt) {
        f32x4 ov = o[dt] * rinv;
        *(f32x4*)(orow + dt * 16) = ov;
    }
}

extern "C" void kernel_launch(void* const* d_in, const int* in_sizes, int n_in,
                              void* d_out, int out_size, void* d_ws, size_t ws_size,
                              hipStream_t stream) {
    const float* x  = (const float*)d_in[0];
    const float* Wq = (const float*)d_in[1];
    const float* bq = (const float*)d_in[2];
    const float* Wk = (const float*)d_in[3];
    const float* bk = (const float*)d_in[4];
    const float* Wv = (const float*)d_in[5];
    const float* bv = (const float*)d_in[6];
    float* out = (float*)d_out;

    char* ws = (char*)d_ws;
    _Float16* Wt   = (_Float16*)(ws + OFF_WT);
    _Float16* Wl   = (_Float16*)(ws + OFF_WLO);
    _Float16* q_hi = (_Float16*)(ws + OFF_QHI);
    _Float16* q_lo = (_Float16*)(ws + OFF_QLO);
    _Float16* k_hi = (_Float16*)(ws + OFF_KHI);
    _Float16* k_lo = (_Float16*)(ws + OFF_KLO);
    _Float16* v_t  = (_Float16*)(ws + OFF_VT);

    prep_w  <<<384, 256, 0, stream>>>(Wq, Wk, Wv, Wt, Wl);
    proj_qkv<<<512, 256, 0, stream>>>(x, Wt, Wl, bq, bk, bv, q_hi, q_lo, k_hi, k_lo, v_t);
    attn    <<<512, 256, 0, stream>>>(q_hi, q_lo, k_hi, k_lo, v_t, out);
}

// Round 3
// 370.824 us; speedup vs baseline: 1.5363x; 1.5363x over previous
//
#include <hip/hip_runtime.h>

#define BATCH 16
#define SEQ   2048
#define EMB   1024
#define DH    128

typedef _Float16 half4_t __attribute__((ext_vector_type(4)));
typedef _Float16 half8_t __attribute__((ext_vector_type(8)));
typedef float    f32x4   __attribute__((ext_vector_type(4)));

// ---------------- workspace layout (bytes) ----------------
// Wt2  : packed W tiles, 32 kc x 40KB (hi 24KB + lo 16KB) = 1.25 MB @ 0
// q_hi : [32768][128] f16 (scaled by 32*log2e)  @ 2 MB (8 MB each region)
#define OFF_WT2 0u
#define OFF_QHI 0x200000u
#define OFF_QLO (OFF_QHI + 0x800000u)
#define OFF_KHI (OFF_QLO + 0x800000u)
#define OFF_KLO (OFF_KHI + 0x800000u)
#define OFF_VT  (OFF_KLO + 0x800000u)

// async global->LDS, 16B per lane (dst = wave-uniform base + lane*16)
__device__ __forceinline__ void gload16(const void* g, void* l) {
    __builtin_amdgcn_global_load_lds(
        (__attribute__((address_space(1))) const unsigned int*)g,
        (__attribute__((address_space(3))) unsigned int*)l, 16, 0, 0);
}

// ---------------- kernel 1: pack W into MFMA-fragment order ----------------
// Wt2[kc] = 40KB: hi: 24 ntiles (8q,8k,8v) x [g(4)][r(16)] 16B chunks (8 f16,
// k = kc*32+g*8+j, col = ntile*16+r); then lo: 16 ntiles (8q,8k) residuals.
__global__ __launch_bounds__(256) void prep_w(
    const float* __restrict__ Wq, const float* __restrict__ Wk,
    const float* __restrict__ Wv, _Float16* __restrict__ Wt2) {
    const int t  = blockIdx.x * 256 + threadIdx.x;   // 0..81919
    const int kc = t / 2560, rem = t % 2560;
    const int lo = rem >= 1536 ? 1 : 0;
    const int rr = lo ? rem - 1536 : rem;
    const int nt = rr >> 6, c = rr & 63;             // c = g*16 + r
    const int g = c >> 4, r = c & 15;
    const int k0 = kc * 32 + g * 8;
    const float* W; int col;
    if (nt < 8)       { W = Wq; col = nt * 16 + r; }
    else if (nt < 16) { W = Wk; col = (nt - 8) * 16 + r; }
    else              { W = Wv; col = (nt - 16) * 16 + r; }
    half8_t v;
#pragma unroll
    for (int j = 0; j < 8; ++j) {
        float f = W[(size_t)(k0 + j) * DH + col];
        _Float16 h = (_Float16)f;
        v[j] = lo ? (_Float16)(f - (float)h) : h;
    }
    *(half8_t*)((char*)Wt2 + (size_t)kc * 40960 + (lo ? 24576 : 0)
                + (size_t)nt * 1024 + c * 16) = v;
}

// ---------------- kernel 2: QKV projection (LDS-staged GEMM) ----------------
// Block: 4 waves, BM=64 rows, N=384 full. Per K-step(32): stage x (8KB fp32,
// source-swizzled) + W chunk (40KB, linear) via global_load_lds; wave w
// computes 64 rows x 6 ntiles {q:w,w+4; k:8+w,12+w; v:16+w,20+w}.
#define XOFF   0
#define WHIOFF 8192
#define WLOOFF 32768

__global__ __launch_bounds__(256) void proj_qkv(
    const float* __restrict__ x, const _Float16* __restrict__ Wt2,
    const float* __restrict__ bq, const float* __restrict__ bk,
    const float* __restrict__ bv,
    _Float16* __restrict__ qhi, _Float16* __restrict__ qlo,
    _Float16* __restrict__ khi, _Float16* __restrict__ klo,
    _Float16* __restrict__ vt) {
    __shared__ __align__(16) char lds[49152];
    const int tid = threadIdx.x, lane = tid & 63, w = tid >> 6;
    const int l15 = lane & 15, g = lane >> 4;
    const int m0  = blockIdx.x * 64;

    f32x4 acc[4][6];
#pragma unroll
    for (int mt = 0; mt < 4; ++mt)
#pragma unroll
        for (int j = 0; j < 6; ++j) acc[mt][j] = {};

    for (int kc = 0; kc < 32; ++kc) {
        __syncthreads();
        // ---- stage x: rows m0..m0+63, k kc*32..+32 (fp32, 8KB). LDS chunk c
        // holds global chunk ((c&7)^(r&7)) of row r=c>>3  (m173 source-swizzle).
        for (int i = 0; i < 2; ++i) {
            const int cbase = w * 128 + i * 64;
            const int c = cbase + lane;
            const int r = c >> 3;
            const int cc = (c & 7) ^ (r & 7);
            gload16(x + (size_t)(m0 + r) * EMB + kc * 32 + cc * 4,
                    lds + XOFF + cbase * 16);
        }
        // ---- stage W chunk: 40KB fully linear (pre-packed fragment order)
        const char* wsrc = (const char*)Wt2 + (size_t)kc * 40960;
        for (int i = 0; i < 10; ++i) {
            const int off = (w * 10 + i) * 1024;
            gload16(wsrc + off + lane * 16, lds + WHIOFF + off);
        }
        __syncthreads();   // compiler drains vmcnt(0) before barrier

        // ---- A fragments: 4 m-tiles, fp32 -> f16 hi/lo
        half8_t xh[4], xl[4];
#pragma unroll
        for (int mt = 0; mt < 4; ++mt) {
            const int row = mt * 16 + l15;
            const int sw = row & 7;
            f32x4 a0 = *(const f32x4*)(lds + XOFF + row * 128 + (((g << 1))     ^ sw) * 16);
            f32x4 a1 = *(const f32x4*)(lds + XOFF + row * 128 + (((g << 1) | 1) ^ sw) * 16);
#pragma unroll
            for (int j = 0; j < 4; ++j) {
                float f = a0[j]; _Float16 h = (_Float16)f;
                xh[mt][j] = h; xl[mt][j] = (_Float16)(f - (float)h);
                float f2 = a1[j]; _Float16 h2 = (_Float16)f2;
                xh[mt][j + 4] = h2; xl[mt][j + 4] = (_Float16)(f2 - (float)h2);
            }
        }
        // ---- MFMAs: 6 n-tiles; q,k 3-pass hi/lo, v 1-pass
#pragma unroll
        for (int j = 0; j < 6; ++j) {
            const int nt = (j >> 1) * 8 + (j & 1) * 4 + w;
            half8_t bh = *(const half8_t*)(lds + WHIOFF + nt * 1024 + g * 256 + l15 * 16);
            if (j < 4) {
                half8_t bl = *(const half8_t*)(lds + WLOOFF + nt * 1024 + g * 256 + l15 * 16);
#pragma unroll
                for (int mt = 0; mt < 4; ++mt) {
                    acc[mt][j] = __builtin_amdgcn_mfma_f32_16x16x32_f16(xh[mt], bh, acc[mt][j], 0, 0, 0);
                    acc[mt][j] = __builtin_amdgcn_mfma_f32_16x16x32_f16(xl[mt], bh, acc[mt][j], 0, 0, 0);
                    acc[mt][j] = __builtin_amdgcn_mfma_f32_16x16x32_f16(xh[mt], bl, acc[mt][j], 0, 0, 0);
                }
            } else {
#pragma unroll
                for (int mt = 0; mt < 4; ++mt)
                    acc[mt][j] = __builtin_amdgcn_mfma_f32_16x16x32_f16(xh[mt], bh, acc[mt][j], 0, 0, 0);
            }
        }
    }

    // ---- epilogue ----
    const float SC = 46.166241308446828f;  // 32 * log2(e), folded into q
#pragma unroll
    for (int j = 0; j < 6; ++j) {
        const int nt = (j >> 1) * 8 + (j & 1) * 4 + w;
#pragma unroll
        for (int mt = 0; mt < 4; ++mt) {
            f32x4 a = acc[mt][j];
            if (j < 2) {                     // q
                const int n = nt * 16 + l15;
                const float bias = bq[n];
#pragma unroll
                for (int ri = 0; ri < 4; ++ri) {
                    const size_t m = m0 + mt * 16 + g * 4 + ri;
                    float qv = (a[ri] + bias) * SC;
                    _Float16 h = (_Float16)qv;
                    qhi[m * DH + n] = h;
                    qlo[m * DH + n] = (_Float16)(qv - (float)h);
                }
            } else if (j < 4) {              // k
                const int d = (nt - 8) * 16 + l15;
                const float bias = bk[d];
#pragma unroll
                for (int ri = 0; ri < 4; ++ri) {
                    const size_t m = m0 + mt * 16 + g * 4 + ri;
                    float kv = a[ri] + bias;
                    _Float16 h = (_Float16)kv;
                    khi[m * DH + d] = h;
                    klo[m * DH + d] = (_Float16)(kv - (float)h);
                }
            } else {                         // v (transposed store)
                const int d = (nt - 16) * 16 + l15;
                const float bias = bv[d];
                const int bb = m0 >> 11;
                const int s0 = (m0 & (SEQ - 1)) + mt * 16 + g * 4;
                half4_t vv;
#pragma unroll
                for (int ri = 0; ri < 4; ++ri) vv[ri] = (_Float16)(a[ri] + bias);
                *(half4_t*)(vt + (size_t)bb * DH * SEQ + (size_t)d * SEQ + s0) = vv;
            }
        }
    }
}

// ---------------- kernel 3: causal flash attention (unchanged) ----------------
__global__ __launch_bounds__(256) void attn(
    const _Float16* __restrict__ qhi, const _Float16* __restrict__ qlo,
    const _Float16* __restrict__ khi, const _Float16* __restrict__ klo,
    const _Float16* __restrict__ vt, float* __restrict__ out) {
    const int lane = threadIdx.x & 63;
    const int w    = threadIdx.x >> 6;
    const int l15  = lane & 15, g = lane >> 4;

    const int gid = blockIdx.x;
    const int xcd = gid & 7, ix = gid >> 3;
    const int b   = (xcd << 1) | (ix & 1);
    const int bx  = ix >> 1;
    const int qt  = bx + w * 32;
    const int q0  = qt * 16;

    const size_t qrow = ((size_t)b * SEQ + q0 + l15) * DH;
    half8_t Qh[4], Ql[4];
#pragma unroll
    for (int kk = 0; kk < 4; ++kk) {
        Qh[kk] = *(const half8_t*)(qhi + qrow + kk * 32 + g * 8);
        Ql[kk] = *(const half8_t*)(qlo + qrow + kk * 32 + g * 8);
    }

    f32x4 o[8];
#pragma unroll
    for (int dt = 0; dt < 8; ++dt) o[dt] = {};
    float mrun = -3.0e38f, ell = 0.0f;

    const _Float16* kb_h  = khi + (size_t)b * SEQ * DH;
    const _Float16* kb_l  = klo + (size_t)b * SEQ * DH;
    const _Float16* vbase = vt  + (size_t)b * DH * SEQ;

    for (int t = 0; t <= qt; ++t) {
        const int kb = t * 16;
        const _Float16* krh = kb_h + (size_t)(kb + l15) * DH + g * 8;
        const _Float16* krl = kb_l + (size_t)(kb + l15) * DH + g * 8;

        f32x4 sa = {}, sb = {};
#pragma unroll
        for (int kk = 0; kk < 4; ++kk) {
            half8_t kh = *(const half8_t*)(krh + kk * 32);
            half8_t kl = *(const half8_t*)(krl + kk * 32);
            sa = __builtin_amdgcn_mfma_f32_16x16x32_f16(kh, Qh[kk], sa, 0, 0, 0);
            sb = __builtin_amdgcn_mfma_f32_16x16x32_f16(kl, Qh[kk], sb, 0, 0, 0);
            sb = __builtin_amdgcn_mfma_f32_16x16x32_f16(kh, Ql[kk], sb, 0, 0, 0);
        }
        f32x4 s = sa + sb;

        if (t == qt) {
#pragma unroll
            for (int r = 0; r < 4; ++r)
                if (kb + g * 4 + r > q0 + l15) s[r] = -3.0e38f;
        }

        float mt = fmaxf(fmaxf(s[0], s[1]), fmaxf(s[2], s[3]));
        mt = fmaxf(mt, __shfl_xor(mt, 16, 64));
        mt = fmaxf(mt, __shfl_xor(mt, 32, 64));
        const float mnew  = fmaxf(mrun, mt);
        const float alpha = exp2f(mrun - mnew);
        const float p0 = exp2f(s[0] - mnew), p1 = exp2f(s[1] - mnew);
        const float p2 = exp2f(s[2] - mnew), p3 = exp2f(s[3] - mnew);
        float ps = p0 + p1 + p2 + p3;
        ps += __shfl_xor(ps, 16, 64);
        ps += __shfl_xor(ps, 32, 64);
        ell = ell * alpha + ps;
        mrun = mnew;

        half4_t pf;
        pf[0] = (_Float16)p0; pf[1] = (_Float16)p1;
        pf[2] = (_Float16)p2; pf[3] = (_Float16)p3;

        const _Float16* vcol = vbase + (size_t)l15 * SEQ + kb + g * 4;
#pragma unroll
        for (int dt = 0; dt < 8; ++dt) {
            half4_t vf = *(const half4_t*)(vcol + (size_t)dt * 16 * SEQ);
            o[dt][0] *= alpha; o[dt][1] *= alpha;
            o[dt][2] *= alpha; o[dt][3] *= alpha;
            o[dt] = __builtin_amdgcn_mfma_f32_16x16x16f16(vf, pf, o[dt], 0, 0, 0);
        }
    }

    const float rinv = 1.0f / ell;
    float* orow = out + ((size_t)b * SEQ + q0 + l15) * DH + g * 4;
#pragma unroll
    for (int dt = 0; dt < 8; ++dt) {
        f32x4 ov = o[dt] * rinv;
        *(f32x4*)(orow + dt * 16) = ov;
    }
}

extern "C" void kernel_launch(void* const* d_in, const int* in_sizes, int n_in,
                              void* d_out, int out_size, void* d_ws, size_t ws_size,
                              hipStream_t stream) {
    const float* x  = (const float*)d_in[0];
    const float* Wq = (const float*)d_in[1];
    const float* bq = (const float*)d_in[2];
    const float* Wk = (const float*)d_in[3];
    const float* bk = (const float*)d_in[4];
    const float* Wv = (const float*)d_in[5];
    const float* bv = (const float*)d_in[6];
    float* out = (float*)d_out;

    char* ws = (char*)d_ws;
    _Float16* Wt2  = (_Float16*)(ws + OFF_WT2);
    _Float16* q_hi = (_Float16*)(ws + OFF_QHI);
    _Float16* q_lo = (_Float16*)(ws + OFF_QLO);
    _Float16* k_hi = (_Float16*)(ws + OFF_KHI);
    _Float16* k_lo = (_Float16*)(ws + OFF_KLO);
    _Float16* v_t  = (_Float16*)(ws + OFF_VT);

    prep_w  <<<320, 256, 0, stream>>>(Wq, Wk, Wv, Wt2);
    proj_qkv<<<512, 256, 0, stream>>>(x, Wt2, bq, bk, bv, q_hi, q_lo, k_hi, k_lo, v_t);
    attn    <<<512, 256, 0, stream>>>(q_hi, q_lo, k_hi, k_lo, v_t, out);
}

// Round 4
// 214.943 us; speedup vs baseline: 2.6505x; 1.7252x over previous
//
#include <hip/hip_runtime.h>

#define BATCH 16
#define SEQ   2048
#define EMB   1024
#define DH    128

typedef _Float16 half4_t __attribute__((ext_vector_type(4)));
typedef _Float16 half8_t __attribute__((ext_vector_type(8)));
typedef float    f32x4   __attribute__((ext_vector_type(4)));

// ---------------- workspace layout (bytes) ----------------
#define OFF_WT2 0u
#define OFF_QHI 0x200000u
#define OFF_QLO (OFF_QHI + 0x800000u)
#define OFF_KHI (OFF_QLO + 0x800000u)
#define OFF_KLO (OFF_KHI + 0x800000u)
#define OFF_VT  (OFF_KLO + 0x800000u)

// async global->LDS, 16B per lane (dst = wave-uniform base + lane*16)
__device__ __forceinline__ void gload16(const void* g, void* l) {
    __builtin_amdgcn_global_load_lds(
        (__attribute__((address_space(1))) const unsigned int*)g,
        (__attribute__((address_space(3))) unsigned int*)l, 16, 0, 0);
}

// ---------------- kernel 1: pack W into MFMA-fragment order ----------------
__global__ __launch_bounds__(256) void prep_w(
    const float* __restrict__ Wq, const float* __restrict__ Wk,
    const float* __restrict__ Wv, _Float16* __restrict__ Wt2) {
    const int t  = blockIdx.x * 256 + threadIdx.x;   // 0..81919
    const int kc = t / 2560, rem = t % 2560;
    const int lo = rem >= 1536 ? 1 : 0;
    const int rr = lo ? rem - 1536 : rem;
    const int nt = rr >> 6, c = rr & 63;             // c = g*16 + r
    const int g = c >> 4, r = c & 15;
    const int k0 = kc * 32 + g * 8;
    const float* W; int col;
    if (nt < 8)       { W = Wq; col = nt * 16 + r; }
    else if (nt < 16) { W = Wk; col = (nt - 8) * 16 + r; }
    else              { W = Wv; col = (nt - 16) * 16 + r; }
    half8_t v;
#pragma unroll
    for (int j = 0; j < 8; ++j) {
        float f = W[(size_t)(k0 + j) * DH + col];
        _Float16 h = (_Float16)f;
        v[j] = lo ? (_Float16)(f - (float)h) : h;
    }
    *(half8_t*)((char*)Wt2 + (size_t)kc * 40960 + (lo ? 24576 : 0)
                + (size_t)nt * 1024 + c * 16) = v;
}

// ---------------- kernel 2: QKV projection (LDS-staged GEMM) ----------------
#define XOFF   0
#define WHIOFF 8192
#define WLOOFF 32768

__global__ __launch_bounds__(256) void proj_qkv(
    const float* __restrict__ x, const _Float16* __restrict__ Wt2,
    const float* __restrict__ bq, const float* __restrict__ bk,
    const float* __restrict__ bv,
    _Float16* __restrict__ qhi, _Float16* __restrict__ qlo,
    _Float16* __restrict__ khi, _Float16* __restrict__ klo,
    _Float16* __restrict__ vt) {
    __shared__ __align__(16) char lds[49152];
    const int tid = threadIdx.x, lane = tid & 63, w = tid >> 6;
    const int l15 = lane & 15, g = lane >> 4;
    const int m0  = blockIdx.x * 64;

    f32x4 acc[4][6];
#pragma unroll
    for (int mt = 0; mt < 4; ++mt)
#pragma unroll
        for (int j = 0; j < 6; ++j) acc[mt][j] = {};

    for (int kc = 0; kc < 32; ++kc) {
        __syncthreads();
        for (int i = 0; i < 2; ++i) {
            const int cbase = w * 128 + i * 64;
            const int c = cbase + lane;
            const int r = c >> 3;
            const int cc = (c & 7) ^ (r & 7);
            gload16(x + (size_t)(m0 + r) * EMB + kc * 32 + cc * 4,
                    lds + XOFF + cbase * 16);
        }
        const char* wsrc = (const char*)Wt2 + (size_t)kc * 40960;
        for (int i = 0; i < 10; ++i) {
            const int off = (w * 10 + i) * 1024;
            gload16(wsrc + off + lane * 16, lds + WHIOFF + off);
        }
        __syncthreads();

        half8_t xh[4], xl[4];
#pragma unroll
        for (int mt = 0; mt < 4; ++mt) {
            const int row = mt * 16 + l15;
            const int sw = row & 7;
            f32x4 a0 = *(const f32x4*)(lds + XOFF + row * 128 + (((g << 1))     ^ sw) * 16);
            f32x4 a1 = *(const f32x4*)(lds + XOFF + row * 128 + (((g << 1) | 1) ^ sw) * 16);
#pragma unroll
            for (int j = 0; j < 4; ++j) {
                float f = a0[j]; _Float16 h = (_Float16)f;
                xh[mt][j] = h; xl[mt][j] = (_Float16)(f - (float)h);
                float f2 = a1[j]; _Float16 h2 = (_Float16)f2;
                xh[mt][j + 4] = h2; xl[mt][j + 4] = (_Float16)(f2 - (float)h2);
            }
        }
#pragma unroll
        for (int j = 0; j < 6; ++j) {
            const int nt = (j >> 1) * 8 + (j & 1) * 4 + w;
            half8_t bh = *(const half8_t*)(lds + WHIOFF + nt * 1024 + g * 256 + l15 * 16);
            if (j < 4) {
                half8_t bl = *(const half8_t*)(lds + WLOOFF + nt * 1024 + g * 256 + l15 * 16);
#pragma unroll
                for (int mt = 0; mt < 4; ++mt) {
                    acc[mt][j] = __builtin_amdgcn_mfma_f32_16x16x32_f16(xh[mt], bh, acc[mt][j], 0, 0, 0);
                    acc[mt][j] = __builtin_amdgcn_mfma_f32_16x16x32_f16(xl[mt], bh, acc[mt][j], 0, 0, 0);
                    acc[mt][j] = __builtin_amdgcn_mfma_f32_16x16x32_f16(xh[mt], bl, acc[mt][j], 0, 0, 0);
                }
            } else {
#pragma unroll
                for (int mt = 0; mt < 4; ++mt)
                    acc[mt][j] = __builtin_amdgcn_mfma_f32_16x16x32_f16(xh[mt], bh, acc[mt][j], 0, 0, 0);
            }
        }
    }

    const float SC = 46.166241308446828f;  // 32 * log2(e), folded into q
#pragma unroll
    for (int j = 0; j < 6; ++j) {
        const int nt = (j >> 1) * 8 + (j & 1) * 4 + w;
#pragma unroll
        for (int mt = 0; mt < 4; ++mt) {
            f32x4 a = acc[mt][j];
            if (j < 2) {                     // q
                const int n = nt * 16 + l15;
                const float bias = bq[n];
#pragma unroll
                for (int ri = 0; ri < 4; ++ri) {
                    const size_t m = m0 + mt * 16 + g * 4 + ri;
                    float qv = (a[ri] + bias) * SC;
                    _Float16 h = (_Float16)qv;
                    qhi[m * DH + n] = h;
                    qlo[m * DH + n] = (_Float16)(qv - (float)h);
                }
            } else if (j < 4) {              // k
                const int d = (nt - 8) * 16 + l15;
                const float bias = bk[d];
#pragma unroll
                for (int ri = 0; ri < 4; ++ri) {
                    const size_t m = m0 + mt * 16 + g * 4 + ri;
                    float kv = a[ri] + bias;
                    _Float16 h = (_Float16)kv;
                    khi[m * DH + d] = h;
                    klo[m * DH + d] = (_Float16)(kv - (float)h);
                }
            } else {                         // v (transposed store)
                const int d = (nt - 16) * 16 + l15;
                const float bias = bv[d];
                const int bb = m0 >> 11;
                const int s0 = (m0 & (SEQ - 1)) + mt * 16 + g * 4;
                half4_t vv;
#pragma unroll
                for (int ri = 0; ri < 4; ++ri) vv[ri] = (_Float16)(a[ri] + bias);
                *(half4_t*)(vt + (size_t)bb * DH * SEQ + (size_t)d * SEQ + s0) = vv;
            }
        }
    }
}

// ---------------- kernel 3: block-cooperative causal flash attention ----------------
// Block = 4 waves sharing one 64-row q-tile (wave w: rows q0+16w..+16).
// KV tiles of 32 staged in LDS (K hi 8KB | K lo 8KB | V^T 8KB), double-buffered.
// Pairing (j, 31-j) -> every block does exactly 66 kv-iterations. 256 blocks.
__global__ __launch_bounds__(256) void attn(
    const _Float16* __restrict__ qhi, const _Float16* __restrict__ qlo,
    const _Float16* __restrict__ khi, const _Float16* __restrict__ klo,
    const _Float16* __restrict__ vt, float* __restrict__ out) {
    __shared__ __align__(16) char lds[49152];
    const int tid = threadIdx.x, lane = tid & 63, w = tid >> 6;
    const int l15 = lane & 15, g = lane >> 4;
    const int gid = blockIdx.x;
    const int b   = ((gid & 7) << 1) | ((gid >> 3) & 1);  // 2 batches per XCD
    const int pr  = gid >> 4;                              // pair index 0..15

    const _Float16* kh_b = khi + (size_t)b * SEQ * DH;
    const _Float16* kl_b = klo + (size_t)b * SEQ * DH;
    const _Float16* v_b  = vt  + (size_t)b * DH * SEQ;

    // stage kv tile t into buffer buf (LDS linear dst, pre-swizzled source)
    auto stage = [&](int t, int buf) {
        const int kb = t * 32;
        char* dst = lds + buf * 24576;
#pragma unroll
        for (int i = 0; i < 2; ++i) {
            const int call = w * 2 + i;
            const int r  = call * 4 + (lane >> 4);           // kv row 0..31
            const int cc = (lane & 15) ^ (r & 7);            // 16B chunk swizzle
            gload16(kh_b + (size_t)(kb + r) * DH + cc * 8, dst + call * 1024);
            gload16(kl_b + (size_t)(kb + r) * DH + cc * 8, dst + 8192 + call * 1024);
            const int dh = call * 16 + (lane >> 2);          // dh row 0..127
            const int c2 = (lane & 3) ^ (dh & 3);
            gload16(v_b + (size_t)dh * SEQ + kb + c2 * 8, dst + 16384 + call * 1024);
        }
    };

    for (int pass = 0; pass < 2; ++pass) {
        const int jt  = pass ? 31 - pr : pr;
        const int q0  = jt * 64;
        const int qw0 = q0 + w * 16;
        const int nkv = 2 * (jt + 1);

        const size_t qrow = ((size_t)b * SEQ + qw0 + l15) * DH;
        half8_t Qh[4], Ql[4];
#pragma unroll
        for (int kk = 0; kk < 4; ++kk) {
            Qh[kk] = *(const half8_t*)(qhi + qrow + kk * 32 + g * 8);
            Ql[kk] = *(const half8_t*)(qlo + qrow + kk * 32 + g * 8);
        }

        f32x4 o[8];
#pragma unroll
        for (int dt = 0; dt < 8; ++dt) o[dt] = {};
        float mrun = -3.0e38f, ell = 0.0f;

        __syncthreads();             // previous pass done with LDS
        stage(0, 0);

        for (int t = 0; t < nkv; ++t) {
            __syncthreads();         // buf[t&1] staged (vmcnt drained at barrier)
            if (t + 1 < nkv) stage(t + 1, (t + 1) & 1);

            const int kb = t * 32;
            if (kb <= qw0 + 15) {    // wave-uniform: skip fully-masked tiles
                const char* kbuf = lds + (t & 1) * 24576;
                const int sw = l15 & 7;

                f32x4 sa0 = {}, sb0 = {}, sa1 = {}, sb1 = {};
#pragma unroll
                for (int kk = 0; kk < 4; ++kk) {
                    const int ch = ((kk * 4 + g) ^ sw) * 16;
                    half8_t kh0 = *(const half8_t*)(kbuf + l15 * 256 + ch);
                    half8_t kl0 = *(const half8_t*)(kbuf + 8192 + l15 * 256 + ch);
                    half8_t kh1 = *(const half8_t*)(kbuf + (16 + l15) * 256 + ch);
                    half8_t kl1 = *(const half8_t*)(kbuf + 8192 + (16 + l15) * 256 + ch);
                    sa0 = __builtin_amdgcn_mfma_f32_16x16x32_f16(kh0, Qh[kk], sa0, 0, 0, 0);
                    sb0 = __builtin_amdgcn_mfma_f32_16x16x32_f16(kl0, Qh[kk], sb0, 0, 0, 0);
                    sb0 = __builtin_amdgcn_mfma_f32_16x16x32_f16(kh0, Ql[kk], sb0, 0, 0, 0);
                    sa1 = __builtin_amdgcn_mfma_f32_16x16x32_f16(kh1, Qh[kk], sa1, 0, 0, 0);
                    sb1 = __builtin_amdgcn_mfma_f32_16x16x32_f16(kl1, Qh[kk], sb1, 0, 0, 0);
                    sb1 = __builtin_amdgcn_mfma_f32_16x16x32_f16(kh1, Ql[kk], sb1, 0, 0, 0);
                }
                f32x4 s0 = sa0 + sb0, s1 = sa1 + sb1;

                if (kb + 31 > qw0) { // diagonal region: causal mask
#pragma unroll
                    for (int r = 0; r < 4; ++r) {
                        if (kb + g * 4 + r      > qw0 + l15) s0[r] = -3.0e38f;
                        if (kb + 16 + g * 4 + r > qw0 + l15) s1[r] = -3.0e38f;
                    }
                }

                float mt = fmaxf(fmaxf(fmaxf(s0[0], s0[1]), fmaxf(s0[2], s0[3])),
                                 fmaxf(fmaxf(s1[0], s1[1]), fmaxf(s1[2], s1[3])));
                mt = fmaxf(mt, __shfl_xor(mt, 16, 64));
                mt = fmaxf(mt, __shfl_xor(mt, 32, 64));
                if (!__all(mt <= mrun + 8.0f)) {   // defer-max (log2 units)
                    const float mnew = fmaxf(mrun, mt);
                    const float alpha = exp2f(mrun - mnew);
                    ell *= alpha;
#pragma unroll
                    for (int dt = 0; dt < 8; ++dt) o[dt] *= alpha;
                    mrun = mnew;
                }
                float p[8];
#pragma unroll
                for (int r = 0; r < 4; ++r) {
                    p[r]     = exp2f(s0[r] - mrun);
                    p[4 + r] = exp2f(s1[r] - mrun);
                }
                float ps = ((p[0] + p[1]) + (p[2] + p[3])) + ((p[4] + p[5]) + (p[6] + p[7]));
                ps += __shfl_xor(ps, 16, 64);
                ps += __shfl_xor(ps, 32, 64);
                ell += ps;

                half4_t pf0, pf1;
#pragma unroll
                for (int r = 0; r < 4; ++r) { pf0[r] = (_Float16)p[r]; pf1[r] = (_Float16)p[4 + r]; }

                const char* vbuf = kbuf + 16384;
                const int sw2 = l15 & 3;
                const int h8  = (g & 1) * 8;
                const int c0  = (((g >> 1))     ^ sw2) * 16 + h8;
                const int c1  = (((g >> 1) + 2) ^ sw2) * 16 + h8;
#pragma unroll
                for (int dt = 0; dt < 8; ++dt) {
                    const int rowb = (dt * 16 + l15) * 64;
                    half4_t v0 = *(const half4_t*)(vbuf + rowb + c0);
                    half4_t v1 = *(const half4_t*)(vbuf + rowb + c1);
                    o[dt] = __builtin_amdgcn_mfma_f32_16x16x16f16(v0, pf0, o[dt], 0, 0, 0);
                    o[dt] = __builtin_amdgcn_mfma_f32_16x16x16f16(v1, pf1, o[dt], 0, 0, 0);
                }
            }
        }

        const float rinv = 1.0f / ell;
        float* orow = out + ((size_t)b * SEQ + qw0 + l15) * DH + g * 4;
#pragma unroll
        for (int dt = 0; dt < 8; ++dt) {
            f32x4 ov = o[dt] * rinv;
            *(f32x4*)(orow + dt * 16) = ov;
        }
    }
}

extern "C" void kernel_launch(void* const* d_in, const int* in_sizes, int n_in,
                              void* d_out, int out_size, void* d_ws, size_t ws_size,
                              hipStream_t stream) {
    const float* x  = (const float*)d_in[0];
    const float* Wq = (const float*)d_in[1];
    const float* bq = (const float*)d_in[2];
    const float* Wk = (const float*)d_in[3];
    const float* bk = (const float*)d_in[4];
    const float* Wv = (const float*)d_in[5];
    const float* bv = (const float*)d_in[6];
    float* out = (float*)d_out;

    char* ws = (char*)d_ws;
    _Float16* Wt2  = (_Float16*)(ws + OFF_WT2);
    _Float16* q_hi = (_Float16*)(ws + OFF_QHI);
    _Float16* q_lo = (_Float16*)(ws + OFF_QLO);
    _Float16* k_hi = (_Float16*)(ws + OFF_KHI);
    _Float16* k_lo = (_Float16*)(ws + OFF_KLO);
    _Float16* v_t  = (_Float16*)(ws + OFF_VT);

    prep_w  <<<320, 256, 0, stream>>>(Wq, Wk, Wv, Wt2);
    proj_qkv<<<512, 256, 0, stream>>>(x, Wt2, bq, bk, bv, q_hi, q_lo, k_hi, k_lo, v_t);
    attn    <<<256, 256, 0, stream>>>(q_hi, q_lo, k_hi, k_lo, v_t, out);
}